// Round 11
// baseline (722.285 us; speedup 1.0000x reference)
//
#include <hip/hip_runtime.h>
#include <math.h>
#include <stdint.h>

#define N 50000
#define E 600000
#define EPB 16     // edges per pass
#define LDK 104    // padded K stride (bf16 elems) for tp tiles

typedef __attribute__((ext_vector_type(8))) short short8;
typedef __attribute__((ext_vector_type(4))) float float4v;

__device__ __forceinline__ float silu_f(float x) { return x / (1.f + __expf(-x)); }
__device__ __forceinline__ float sigm_f(float x) { return 1.f / (1.f + __expf(-x)); }
__device__ __forceinline__ unsigned short f2bf(float f) {
  unsigned u = __float_as_uint(f);
  u += 0x7fff + ((u >> 16) & 1);   // RNE
  return (unsigned short)(u >> 16);
}
__device__ __forceinline__ float bf2f(unsigned short u) {
  return __uint_as_float(((unsigned)u) << 16);
}

// ---------------- CSR build ----------------
__global__ void k_hist(const int* __restrict__ eidx, int* __restrict__ counts) {
  int e = blockIdx.x * 256 + threadIdx.x;
  if (e < E) atomicAdd(&counts[eidx[E + e]], 1);
}

__global__ __launch_bounds__(1024)
void k_scan(const int* __restrict__ counts, int* __restrict__ row_ptr) {
  __shared__ int ssum[1024];
  const int t = threadIdx.x;
  const int CH = 49;
  int lo = t * CH, hi = min(lo + CH, N);
  int s = 0;
  for (int i = lo; i < hi; i++) s += counts[i];
  ssum[t] = s;
  __syncthreads();
  for (int off = 1; off < 1024; off <<= 1) {
    int v = (t >= off) ? ssum[t - off] : 0;
    __syncthreads();
    ssum[t] += v;
    __syncthreads();
  }
  int run = (t == 0) ? 0 : ssum[t - 1];
  for (int i = lo; i < hi; i++) { row_ptr[i] = run; run += counts[i]; }
  if (t == 1023) row_ptr[N] = ssum[1023];
}

__global__ void k_scatter(const int* __restrict__ eidx, const int* __restrict__ row_ptr,
                          int* __restrict__ woff, int* __restrict__ perm) {
  int e = blockIdx.x * 256 + threadIdx.x;
  if (e < E) {
    int d = eidx[E + e];
    int p = atomicAdd(&woff[d], 1);
    perm[row_ptr[d] + p] = e;
  }
}

// ---------------- Kernel INIT: fused prep + lin1 + zero(cnt/woff) + zero(aggs) ----------------
// All four are mutually independent; block-range partitioned. k_hist stays a
// separate dispatch (it atomically increments cnt -- fusing would race the zeroing).
// Partitions: [0,528) prep | [528,1552) lin1 (1024 virt blocks) | [1552,1943) zero cnt 2N |
// [1943,3943) zero aggs N*160 floats (float4, 16B-aligned).
__global__ __launch_bounds__(256)
void k_init(const float* __restrict__ Wsc0, const float* __restrict__ W3s,
            const float* __restrict__ Wsc1, const float* __restrict__ W3v,
            const float* __restrict__ W2s, const float* __restrict__ W2v,
            unsigned short* __restrict__ BT, unsigned short* __restrict__ B2T,
            unsigned short* __restrict__ w2sTg, unsigned short* __restrict__ w2vTg,
            const float* __restrict__ node_s, const float* __restrict__ node_v,
            const float* __restrict__ W1s, const float* __restrict__ W1v,
            float* __restrict__ s1, float* __restrict__ v1,
            int* __restrict__ cnt, float* __restrict__ aggs) {
  __shared__ float w1s[64 * 64];
  __shared__ float w1v[32 * 32];
  const int b = blockIdx.x, t = threadIdx.x;
  const float isq96 = 0.10206207261596575f;

  if (b < 528) {
    // ---- prep: bf16 transposed B matrices ----
    int i = b * 256 + t;
    if (i < 96 * 1088) {
      int j = i / 1088, k = i % 1088;
      float v;
      if (k < 1024) v = Wsc0[(size_t)k * 96 + j] * 0.03125f;          // 1/sqrt(1024)
      else          v = W3s[(size_t)(k - 1024) * 96 + j] * 0.125f;    // 1/sqrt(64)
      BT[i] = f2bf(v);
    } else if (i < 96 * 1088 + 32 * 576) {
      int i2 = i - 96 * 1088;
      int w = i2 / 576, k = i2 % 576;
      float v = 0.f;
      if (k < 512)      v = Wsc1[(size_t)k * 32 + w] * 0.04419417382415922f;  // 1/sqrt(512)
      else if (k < 544) v = W3v[(size_t)(k - 512) * 32 + w] * 0.17677669529663689f; // 1/sqrt(32)
      B2T[i2] = f2bf(v);
    } else if (i < 96 * 1088 + 32 * 576 + 96 * 96) {
      int i3 = i - (96 * 1088 + 32 * 576);
      int j = i3 / 96, k = i3 % 96;            // w2sTg[j][k] = W2s[k][j]
      w2sTg[i3] = f2bf(W2s[(size_t)k * 96 + j] * isq96);
    } else {
      int i4 = i - (96 * 1088 + 32 * 576 + 96 * 96);
      if (i4 < 32 * 96) {
        int v = i4 / 96, u = i4 % 96;          // w2vTg[v][u] = W2v[u][v]
        w2vTg[i4] = f2bf(W2v[(size_t)u * 32 + v] * isq96);
      }
    }
  } else if (b < 1552) {
    // ---- lin1: s1 = node_s@W1s/8 ; v1 = node_v x W1v /sqrt(32) ----
    for (int i = t; i < 64 * 64; i += 256) w1s[i] = W1s[i];
    for (int i = t; i < 32 * 32; i += 256) w1v[i] = W1v[i];
    __syncthreads();
    const float is_ns = 0.125f;
    const float is_nv = 0.17677669529663689f;
    int gtid = (b - 528) * 256 + t;
    const int stride = 1024 * 256;
    for (int i = gtid; i < N * 160; i += stride) {
      int n = i / 160, ch = i % 160;
      if (ch < 64) {
        const float* row = node_s + n * 64;
        float acc = 0.f;
#pragma unroll
        for (int u = 0; u < 64; u++) acc += row[u] * w1s[u * 64 + ch];
        s1[n * 64 + ch] = acc * is_ns;
      } else {
        int p = ch - 64, v = p / 3, c = p % 3;
        const float* row = node_v + n * 96;
        float acc = 0.f;
#pragma unroll
        for (int u = 0; u < 32; u++) acc += row[u * 3 + c] * w1v[u * 32 + v];
        v1[n * 96 + p] = acc * is_nv;
      }
    }
  } else if (b < 1943) {
    // ---- zero cnt + woff (2N ints) ----
    if (cnt) {
      int idx = (b - 1552) * 256 + t;
      if (idx < 2 * N) cnt[idx] = 0;
    }
  } else {
    // ---- zero aggs + aggv (N*160 floats, 16B-aligned base) ----
    float4v* a4 = (float4v*)aggs;
    const int tot = N * 160 / 4;
    const float4v z = {0.f, 0.f, 0.f, 0.f};
    for (int i = (b - 1943) * 256 + t; i < tot; i += 2000 * 256) a4[i] = z;
  }
}

// ---------------- Kernel B: streaming per-edge message via MFMA + in-kernel CSR reduce ----------------
// R8: CSR-order edges via perm, segment-reduce in LDS, coalesced f32 atomics.
// R10: fused 12-tile MFMA phase, gate folded into reduce.
// R11: occupancy package -- msL/mvL stored as bf16 (numerically = the proven
// R0-R7 bf16-message path), LDS 34.3 -> ~28.8KB < 32KB, launch_bounds(256,5),
// grid 1280 = exactly 5 blocks/CU (R6 lesson: grid must match residency).
template<int STORE>
__global__ __launch_bounds__(256, 5)
void k_msg(const float* __restrict__ s1, const float* __restrict__ v1,
           const float* __restrict__ emb, const float* __restrict__ sh0g,
           const float* __restrict__ sh1g, const int* __restrict__ eidx,
           const int* __restrict__ perm,
           const float* __restrict__ Wm1, const float* __restrict__ Wm2,
           const unsigned short* __restrict__ w2sTg, const unsigned short* __restrict__ w2vTg,
           float* __restrict__ aggs, float* __restrict__ aggv) {
  __shared__ float wm2s[192 * 9];             // staging, stride 9 (bank-safe)
  __shared__ float wm1s[64];
  __shared__ unsigned short tps[EPB * LDK];
  __shared__ unsigned short tpv[EPB * 3 * LDK];
  __shared__ float gat[EPB][33];              // padded: bank-conflict-free
  __shared__ unsigned short msL[EPB][66];     // per-pass m_s (bf16, silu applied)
  __shared__ unsigned short mvL[EPB][98];     // per-pass m_v (bf16, RAW -- gate in reduce)
  __shared__ float hb[EPB][8];
  __shared__ float sh1b[EPB][4];
  __shared__ float sh0b[EPB];
  __shared__ int ssrc[EPB];
  __shared__ int sdst[EPB];

  const int t = threadIdx.x;
  const int wave = t >> 6, lane = t & 63;
  const int lm = lane & 15, quad = lane >> 4;
  const int subc = t & 15;

  // ---- one-time staging ----
  for (int i = t; i < 192 * 8; i += 256) {
    int h = i / 192, c = i % 192;
    wm2s[c * 9 + h] = Wm2[i];
  }
  if (t < 64) wm1s[t] = Wm1[t];

  // ---- hoist MFMA B-fragments into registers (pass-invariant, AGPR-resident) ----
  short8 b1fr[2][3], b2fr[3];
  {
    const int nt0 = wave;
    const int nt1 = (wave + 4 < 6) ? wave + 4 : wave;   // waves 2,3: dup (unused)
    const int nv2 = wave & 1;                           // GEMM2: same for both tiles
#pragma unroll
    for (int kk = 0; kk < 3; kk++) {
      b1fr[0][kk] = *(const short8*)&w2sTg[(nt0 * 16 + lm) * 96 + kk * 32 + quad * 8];
      b1fr[1][kk] = *(const short8*)&w2sTg[(nt1 * 16 + lm) * 96 + kk * 32 + quad * 8];
      b2fr[kk]    = *(const short8*)&w2vTg[(nv2 * 16 + lm) * 96 + kk * 32 + quad * 8];
    }
  }
  __syncthreads();

  for (int pass = blockIdx.x; pass < E / EPB; pass += gridDim.x) {
    const int ebase = pass * EPB;
    __syncthreads();   // prev pass's reduce/GEMM reads done before overwrite
    // ---- phase A: stage edge meta + radial MLP hidden (disjoint threads) ----
    if (t < EPB) {
      const int e = STORE ? perm[ebase + t] : (ebase + t);
      ssrc[t] = eidx[e];
      sdst[t] = eidx[E + e];
      sh0b[t] = sh0g[e];
    } else if (t >= 64 && t < 64 + EPB * 3) {
      int i = t - 64;
      const int el = i / 3, c = i % 3;
      const int e = STORE ? perm[ebase + el] : (ebase + el);
      sh1b[el][c] = sh1g[e * 3 + c];
    } else if (t >= 128) {
      int i = t - 128, el = i >> 3, sub = i & 7;
      const int e = STORE ? perm[ebase + el] : (ebase + el);
      float acc = 0.f;
#pragma unroll
      for (int r = 0; r < 8; r++) acc += emb[e * 8 + r] * wm1s[r * 8 + sub];
      hb[el][sub] = silu_f(acc);
    }
    __syncthreads();
    // ---- phase B: build TPS / TPV (bf16); Wm2 read explicitly from LDS ----
    {
      const int el = t >> 4, sub = subc;
      const int src = ssrc[el];
      const float s0v = sh0b[el];
      const float x0 = sh1b[el][0], x1 = sh1b[el][1], x2 = sh1b[el][2];
      float hr[8];
#pragma unroll
      for (int h = 0; h < 8; h++) hr[h] = hb[el][h];
      const float4v ss = *(const float4v*)&s1[(size_t)src * 64 + sub * 4];
      unsigned short tsv[4], tvv[3][4];
#pragma unroll
      for (int i = 0; i < 4; i++) {
        float w0a = 0.f, w1a = 0.f;
#pragma unroll
        for (int h = 0; h < 8; h++) {
          w0a += hr[h] * wm2s[(sub * 4 + i) * 9 + h];
          w1a += hr[h] * wm2s[(64 + sub * 4 + i) * 9 + h];
        }
        const float ssu = ss[i];
        tsv[i] = f2bf(w0a * ssu * s0v);
        const float base = w1a * ssu;
        tvv[0][i] = f2bf(base * x0);
        tvv[1][i] = f2bf(base * x1);
        tvv[2][i] = f2bf(base * x2);
      }
      *(uint2*)&tps[el * LDK + sub * 4] = *(uint2*)tsv;
#pragma unroll
      for (int c = 0; c < 3; c++)
        *(uint2*)&tpv[(el * 3 + c) * LDK + sub * 4] = *(uint2*)tvv[c];
      const float2* vp = (const float2*)&v1[(size_t)src * 96 + sub * 6];
      const float2 va = vp[0], vb = vp[1], vc = vp[2];
      const float v6[6] = {va.x, va.y, vb.x, vb.y, vc.x, vc.y};
      unsigned short ts2[2], tv2[3][2];
#pragma unroll
      for (int i2 = 0; i2 < 2; i2++) {
        float w1b = 0.f, w0b = 0.f;
#pragma unroll
        for (int h = 0; h < 8; h++) {
          w1b += hr[h] * wm2s[(128 + sub * 2 + i2) * 9 + h];
          w0b += hr[h] * wm2s[(160 + sub * 2 + i2) * 9 + h];
        }
        const float vx = v6[i2 * 3 + 0], vy = v6[i2 * 3 + 1], vz = v6[i2 * 3 + 2];
        ts2[i2] = f2bf(w0b * (vx * x0 + vy * x1 + vz * x2));
        tv2[0][i2] = f2bf(w1b * vx * s0v);
        tv2[1][i2] = f2bf(w1b * vy * s0v);
        tv2[2][i2] = f2bf(w1b * vz * s0v);
      }
      *(unsigned*)&tps[el * LDK + 64 + sub * 2] = *(unsigned*)ts2;
#pragma unroll
      for (int c = 0; c < 3; c++)
        *(unsigned*)&tpv[(el * 3 + c) * LDK + 64 + sub * 2] = *(unsigned*)tv2[c];
    }
    __syncthreads();
    if (STORE) {
      // ---- fused MFMA phase: 12 tiles (6 G1 + 6 G2), 3 per wave, no idle ----
      short8 afr[3];
#pragma unroll
      for (int kk = 0; kk < 3; kk++)
        afr[kk] = *(const short8*)&tps[lm * LDK + kk * 32 + quad * 8];
#pragma unroll
      for (int tt = 0; tt < 3; tt++) {
        const int id = wave + tt * 4;   // 0..11
        float4v acc = {0.f, 0.f, 0.f, 0.f};
        if (id < 6) {
          // GEMM1 tile nt=id; b1fr index: id==wave -> 0, id==wave+4 -> 1
          const int t2 = id >> 2;
#pragma unroll
          for (int kk = 0; kk < 3; kk++)
            acc = __builtin_amdgcn_mfma_f32_16x16x32_bf16(afr[kk], b1fr[t2][kk], acc, 0, 0, 0);
          const int j = id * 16 + lm;
#pragma unroll
          for (int reg = 0; reg < 4; reg++) {
            const int e = quad * 4 + reg;
            const float val = acc[reg];
            if (j < 64) msL[e][j] = f2bf(silu_f(val));
            else        gat[e][j - 64] = sigm_f(val);
          }
        } else {
          // GEMM2 tile g2=id-6: mt=g2>>1, nt2=g2&1 (nt2 == wave&1 always)
          const int g2 = id - 6;
          const int mt = g2 >> 1, nt2 = g2 & 1;
#pragma unroll
          for (int kk = 0; kk < 3; kk++) {
            short8 a = *(const short8*)&tpv[(mt * 16 + lm) * LDK + kk * 32 + quad * 8];
            acc = __builtin_amdgcn_mfma_f32_16x16x32_bf16(a, b2fr[kk], acc, 0, 0, 0);
          }
          const int v = nt2 * 16 + lm;
#pragma unroll
          for (int reg = 0; reg < 4; reg++) {
            const int r = mt * 16 + quad * 4 + reg;
            const int e = (r * 171) >> 9, c = r - 3 * e;
            mvL[e][v * 3 + c] = f2bf(acc[reg]);   // RAW: gate applied in reduce
          }
        }
      }
      __syncthreads();
      // ---- segment-reduce over consecutive equal-dst slots; gate folded in ----
      if (t < 160) {
        const int col = t - 64;                 // valid for t >= 64
        const int gv = (col * 171) >> 9;        // col/3
        float acc = 0.f;
        int cur = sdst[0];
        for (int s2 = 0; s2 < EPB; s2++) {
          const int d = sdst[s2];               // wave-uniform
          const float val = (t < 64) ? bf2f(msL[s2][t])
                                     : bf2f(mvL[s2][col]) * gat[s2][gv];
          if (d != cur) {
            if (t < 64) atomicAdd(&aggs[(size_t)cur * 64 + t], acc);
            else        atomicAdd(&aggv[(size_t)cur * 96 + col], acc);
            acc = 0.f; cur = d;
          }
          acc += val;
        }
        if (t < 64) atomicAdd(&aggs[(size_t)cur * 64 + t], acc);
        else        atomicAdd(&aggv[(size_t)cur * 96 + col], acc);
      }
    } else {
      // ---- fallback: GEMM1 -> barrier -> GEMM2, per-edge atomics ----
      {
        short8 afr[3];
#pragma unroll
        for (int kk = 0; kk < 3; kk++)
          afr[kk] = *(const short8*)&tps[lm * LDK + kk * 32 + quad * 8];
#pragma unroll
        for (int t2 = 0; t2 < 2; t2++) {
          const int nt = wave + t2 * 4;
          if (nt < 6) {
            float4v acc = {0.f, 0.f, 0.f, 0.f};
#pragma unroll
            for (int kk = 0; kk < 3; kk++)
              acc = __builtin_amdgcn_mfma_f32_16x16x32_bf16(afr[kk], b1fr[t2][kk], acc, 0, 0, 0);
            const int j = nt * 16 + lm;
#pragma unroll
            for (int reg = 0; reg < 4; reg++) {
              const int e = quad * 4 + reg;
              const float val = acc[reg];
              if (j < 64) atomicAdd(&aggs[(size_t)sdst[e] * 64 + j], silu_f(val));
              else        gat[e][j - 64] = sigm_f(val);
            }
          }
        }
      }
      __syncthreads();
#pragma unroll
      for (int t2 = 0; t2 < 2; t2++) {
        const int tile = wave + t2 * 4;
        if (tile < 6) {
          const int mt = tile >> 1, nt2 = tile & 1;
          float4v acc = {0.f, 0.f, 0.f, 0.f};
#pragma unroll
          for (int kk = 0; kk < 3; kk++) {
            short8 a = *(const short8*)&tpv[(mt * 16 + lm) * LDK + kk * 32 + quad * 8];
            acc = __builtin_amdgcn_mfma_f32_16x16x32_bf16(a, b2fr[kk], acc, 0, 0, 0);
          }
          const int v = nt2 * 16 + lm;
#pragma unroll
          for (int reg = 0; reg < 4; reg++) {
            const int r = mt * 16 + quad * 4 + reg;
            const int e = (r * 171) >> 9, c = r - 3 * e;
            atomicAdd(&aggv[(size_t)sdst[e] * 96 + v * 3 + c], acc[reg] * gat[e][v]);
          }
        }
      }
    }
  }
}

// ---------------- Kernel C1: MFMA GEMM  [32 nodes x 1088] @ BT^T -> 96 cols ----------------
// R9-proven: per-lane register A-fragments, 2 barriers total, padded LDS rows.
__global__ __launch_bounds__(256, 4)
void k_c1(const float* __restrict__ node_s, const float* __restrict__ attrs,
          const float* __restrict__ aggs, const float* __restrict__ Wt0,
          const unsigned short* __restrict__ BT,
          float* __restrict__ out, float* __restrict__ gates) {
  __shared__ float s_row[32][65];
  __shared__ float attr[32][16];
  __shared__ float t0[32][65];
  __shared__ float wt0[1024];
  const int t = threadIdx.x;
  const int wave = t >> 6, lane = t & 63, lm = lane & 15, quad = lane >> 4;
  const int nbase = blockIdx.x * 32;

  for (int i = t; i < 1024; i += 256) wt0[i] = Wt0[i];
  for (int i = t; i < 2048; i += 256) {
    int nl = i >> 6, u = i & 63, n = nbase + nl;
    s_row[nl][u] = (n < N) ? node_s[(size_t)n * 64 + u] : 0.f;
    t0[nl][u]    = (n < N) ? aggs[(size_t)n * 64 + u] : 0.f;
  }
  for (int i = t; i < 512; i += 256) {
    int nl = i >> 4, a = i & 15, n = nbase + nl;
    attr[nl][a] = (n < N) ? attrs[(size_t)n * 16 + a] : 0.f;
  }
  __syncthreads();
  for (int i = t; i < 2048; i += 256) {
    int nl = i >> 6, u = i & 63;
    float d0 = 0.f;
#pragma unroll
    for (int a = 0; a < 16; a++) d0 += attr[nl][a] * wt0[u * 16 + a];
    t0[nl][u] *= d0 * 0.07216878364870322f;   // 1/(sqrt(16)*sqrt(12))
  }
  __syncthreads();

  // register-cache this lane's attr slices (rows lm and 16+lm, cols (quad&1)*8..+7)
  const int a0 = (quad & 1) * 8;
  float aA0[8], aA1[8];
#pragma unroll
  for (int i = 0; i < 8; i++) {
    aA0[i] = attr[lm][a0 + i];
    aA1[i] = attr[16 + lm][a0 + i];
  }

  float4v acc[3] = {{0,0,0,0},{0,0,0,0},{0,0,0,0}};
  int mts[3], nts[3];
#pragma unroll
  for (int tt = 0; tt < 3; tt++) {
    const int tile = wave + tt * 4;    // 0..11 = mt*6+nt
    mts[tt] = tile / 6;
    nts[tt] = tile % 6;
  }

  for (int kc = 0; kc < 17; kc++) {
#pragma unroll
    for (int ks = 0; ks < 2; ks++) {
      unsigned short e0[8], e1[8];
      if (kc < 16) {
        const int u = kc * 4 + ks * 2 + (quad >> 1);
        const float s0v = s_row[lm][u];
        const float s1v = s_row[16 + lm][u];
#pragma unroll
        for (int i = 0; i < 8; i++) {
          e0[i] = f2bf(s0v * aA0[i]);
          e1[i] = f2bf(s1v * aA1[i]);
        }
      } else {
        const int c0 = ks * 32 + quad * 8;
#pragma unroll
        for (int i = 0; i < 8; i++) {
          e0[i] = f2bf(t0[lm][c0 + i]);
          e1[i] = f2bf(t0[16 + lm][c0 + i]);
        }
      }
      const short8 am0 = *(const short8*)e0;
      const short8 am1 = *(const short8*)e1;
#pragma unroll
      for (int tt = 0; tt < 3; tt++) {
        short8 b = *(const short8*)&BT[(size_t)(nts[tt] * 16 + lm) * 1088 + kc * 64 + ks * 32 + quad * 8];
        acc[tt] = __builtin_amdgcn_mfma_f32_16x16x32_bf16(mts[tt] ? am1 : am0, b, acc[tt], 0, 0, 0);
      }
    }
  }
#pragma unroll
  for (int tt = 0; tt < 3; tt++) {
    const int j = nts[tt] * 16 + lm;
#pragma unroll
    for (int reg = 0; reg < 4; reg++) {
      const int m = mts[tt] * 16 + quad * 4 + reg;
      const int n = nbase + m;
      if (n < N) {
        const float val = acc[tt][reg];
        if (j < 64) out[(size_t)n * 160 + j] = silu_f(val);
        else        gates[(size_t)n * 32 + (j - 64)] = sigm_f(val);
      }
    }
  }
}

// ---------------- Kernel C2: MFMA GEMM  [96 rows (32n x 3c) x 544] @ B2T^T -> 32 cols ----------------
// R9-proven: direct register A-fragments, 2 barriers, kc=8/ks=1 zero-A skipped.
__global__ __launch_bounds__(256, 4)
void k_c2(const float* __restrict__ node_v, const float* __restrict__ attrs,
          const float* __restrict__ aggv, const float* __restrict__ Wt1,
          const unsigned short* __restrict__ B2T, const float* __restrict__ gts,
          float* __restrict__ out) {
  __shared__ float nvs[32][97];
  __shared__ float t1s[32][97];
  __shared__ float attr[32][16];
  __shared__ float wt1[512];
  const int t = threadIdx.x;
  const int wave = t >> 6, lane = t & 63, lm = lane & 15, quad = lane >> 4;
  const int nbase = blockIdx.x * 32;

  for (int i = t; i < 512; i += 256) wt1[i] = Wt1[i];
  for (int i = t; i < 32 * 96; i += 256) {
    int nl = i / 96, rr = i % 96, n = nbase + nl;
    nvs[nl][rr] = (n < N) ? node_v[(size_t)n * 96 + rr] : 0.f;
    t1s[nl][rr] = (n < N) ? aggv[(size_t)n * 96 + rr] : 0.f;
  }
  for (int i = t; i < 512; i += 256) {
    int nl = i >> 4, a = i & 15, n = nbase + nl;
    attr[nl][a] = (n < N) ? attrs[(size_t)n * 16 + a] : 0.f;
  }
  __syncthreads();
  for (int i = t; i < 1024; i += 256) {
    int nl = i >> 5, u = i & 31;
    float d1 = 0.f;
#pragma unroll
    for (int a = 0; a < 16; a++) d1 += attr[nl][a] * wt1[u * 16 + a];
    d1 *= 0.07216878364870322f;
    t1s[nl][u * 3 + 0] *= d1; t1s[nl][u * 3 + 1] *= d1; t1s[nl][u * 3 + 2] *= d1;
  }
  __syncthreads();

  int nls[3], cs[3], nts[3], mts[3];
#pragma unroll
  for (int tt = 0; tt < 3; tt++) {
    const int tile = wave + tt * 4;   // 0..11 = mt*2+nt
    mts[tt] = tile >> 1;
    nts[tt] = tile & 1;
    const int row = mts[tt] * 16 + lm;
    nls[tt] = (row * 171) >> 9;
    cs[tt]  = row - 3 * nls[tt];
  }
  const int a0 = (quad & 1) * 8;
  float aA[3][8];
#pragma unroll
  for (int tt = 0; tt < 3; tt++)
#pragma unroll
    for (int i = 0; i < 8; i++) aA[tt][i] = attr[nls[tt]][a0 + i];

  float4v acc[3] = {{0,0,0,0},{0,0,0,0},{0,0,0,0}};

  for (int kc = 0; kc < 9; kc++) {
#pragma unroll
    for (int ks = 0; ks < 2; ks++) {
      if (kc == 8 && ks == 1) continue;   // k >= 544: A is all-zero
#pragma unroll
      for (int tt = 0; tt < 3; tt++) {
        unsigned short ev[8];
        if (kc < 8) {
          const int u = kc * 4 + ks * 2 + (quad >> 1);
          const float vv = nvs[nls[tt]][u * 3 + cs[tt]];
#pragma unroll
          for (int i = 0; i < 8; i++) ev[i] = f2bf(vv * aA[tt][i]);
        } else {
          // k = 512 + quad*8 + i  (ks == 0)
#pragma unroll
          for (int i = 0; i < 8; i++) ev[i] = f2bf(t1s[nls[tt]][(quad * 8 + i) * 3 + cs[tt]]);
        }
        const short8 a = *(const short8*)ev;
        short8 b = *(const short8*)&B2T[(size_t)(nts[tt] * 16 + lm) * 576 + kc * 64 + ks * 32 + quad * 8];
        acc[tt] = __builtin_amdgcn_mfma_f32_16x16x32_bf16(a, b, acc[tt], 0, 0, 0);
      }
    }
  }
#pragma unroll
  for (int tt = 0; tt < 3; tt++) {
    const int w = nts[tt] * 16 + lm;
#pragma unroll
    for (int reg = 0; reg < 4; reg++) {
      const int row = mts[tt] * 16 + quad * 4 + reg;
      const int nl = (row * 171) >> 9, c = row - 3 * nl;
      const int n = nbase + nl;
      if (n < N)
        out[(size_t)n * 160 + 64 + w * 3 + c] = acc[tt][reg] * gts[(size_t)n * 32 + w];
    }
  }
}

extern "C" void kernel_launch(void* const* d_in, const int* in_sizes, int n_in,
                              void* d_out, int out_size, void* d_ws, size_t ws_size,
                              hipStream_t stream) {
  const float* node_s = (const float*)d_in[0];
  const float* node_v = (const float*)d_in[1];
  const float* attrs  = (const float*)d_in[2];
  const float* emb    = (const float*)d_in[3];
  const float* sh0    = (const float*)d_in[4];
  const float* sh1    = (const float*)d_in[5];
  const int*   eidx   = (const int*)d_in[6];
  const float* W1s    = (const float*)d_in[7];
  const float* W1v    = (const float*)d_in[8];
  const float* Wm1    = (const float*)d_in[9];
  const float* Wm2    = (const float*)d_in[10];
  const float* W2s    = (const float*)d_in[11];
  const float* W2v    = (const float*)d_in[12];
  const float* Wt0    = (const float*)d_in[13];
  const float* Wt1    = (const float*)d_in[14];
  const float* W3s    = (const float*)d_in[15];
  const float* W3v    = (const float*)d_in[16];
  const float* Wsc0   = (const float*)d_in[17];
  const float* Wsc1   = (const float*)d_in[18];

  char* p = (char*)d_ws;
  float* s1  = (float*)p;  p += (size_t)N * 64 * 4;
  float* v1f = (float*)p;  p += (size_t)N * 96 * 4;
  float* gts = (float*)p;  p += (size_t)N * 32 * 4;
  unsigned short* BT    = (unsigned short*)p;  p += (size_t)96 * 1088 * 2;
  unsigned short* B2T   = (unsigned short*)p;  p += (size_t)32 * 576 * 2;
  unsigned short* w2sTg = (unsigned short*)p;  p += (size_t)96 * 96 * 2;
  unsigned short* w2vTg = (unsigned short*)p;  p += (size_t)32 * 96 * 2;
  char* pmode = p;
  size_t base = (size_t)(pmode - (char*)d_ws);
  // store path: rowp + cnt + woff + perm + align + aggs/aggv (f32, contiguous)
  size_t need_store = base + ((size_t)N + 1) * 4 + (size_t)N * 4 + (size_t)N * 4
                    + (size_t)E * 4 + 16 + (size_t)N * 160 * 4;
  const bool store = (ws_size >= need_store);

  if (store) {
    int* rowp = (int*)pmode;
    int* cnt  = rowp + (N + 1);
    int* woff = cnt + N;
    int* perm = woff + N;
    float* aggs = (float*)(((uintptr_t)(perm + E) + 15) & ~(uintptr_t)15);
    float* aggv = aggs + (size_t)N * 64;
    k_init<<<3943, 256, 0, stream>>>(Wsc0, W3s, Wsc1, W3v, W2s, W2v, BT, B2T, w2sTg, w2vTg,
                                     node_s, node_v, W1s, W1v, s1, v1f, cnt, aggs);
    k_hist<<<(E + 255) / 256, 256, 0, stream>>>(eidx, cnt);
    k_scan<<<1, 1024, 0, stream>>>(cnt, rowp);
    k_scatter<<<(E + 255) / 256, 256, 0, stream>>>(eidx, rowp, woff, perm);
    k_msg<1><<<1280, 256, 0, stream>>>(s1, v1f, emb, sh0, sh1, eidx, perm, Wm1, Wm2,
                                       w2sTg, w2vTg, aggs, aggv);
    k_c1<<<1563, 256, 0, stream>>>(node_s, attrs, aggs, Wt0, BT, (float*)d_out, gts);
    k_c2<<<1563, 256, 0, stream>>>(node_v, attrs, aggv, Wt1, B2T, gts, (float*)d_out);
  } else {
    float* aggs = (float*)pmode;
    float* aggv = aggs + (size_t)N * 64;
    k_init<<<3943, 256, 0, stream>>>(Wsc0, W3s, Wsc1, W3v, W2s, W2v, BT, B2T, w2sTg, w2vTg,
                                     node_s, node_v, W1s, W1v, s1, v1f, nullptr, aggs);
    k_msg<0><<<1280, 256, 0, stream>>>(s1, v1f, emb, sh0, sh1, eidx, nullptr, Wm1, Wm2,
                                       w2sTg, w2vTg, aggs, aggv);
    k_c1<<<1563, 256, 0, stream>>>(node_s, attrs, aggs, Wt0, BT, (float*)d_out, gts);
    k_c2<<<1563, 256, 0, stream>>>(node_v, attrs, aggv, Wt1, B2T, gts, (float*)d_out);
  }
}

// Round 12
// 679.705 us; speedup vs baseline: 1.0626x; 1.0626x over previous
//
#include <hip/hip_runtime.h>
#include <math.h>
#include <stdint.h>

#define N 50000
#define E 600000
#define EPB 16     // edges per pass
#define LDK 104    // padded K stride (bf16 elems) for tp tiles

typedef __attribute__((ext_vector_type(8))) short short8;
typedef __attribute__((ext_vector_type(4))) float float4v;

__device__ __forceinline__ float silu_f(float x) { return x / (1.f + __expf(-x)); }
__device__ __forceinline__ float sigm_f(float x) { return 1.f / (1.f + __expf(-x)); }
__device__ __forceinline__ unsigned short f2bf(float f) {
  unsigned u = __float_as_uint(f);
  u += 0x7fff + ((u >> 16) & 1);   // RNE
  return (unsigned short)(u >> 16);
}
__device__ __forceinline__ float bf2f(unsigned short u) {
  return __uint_as_float(((unsigned)u) << 16);
}

// ---------------- CSR build ----------------
__global__ void k_hist(const int* __restrict__ eidx, int* __restrict__ counts) {
  int e = blockIdx.x * 256 + threadIdx.x;
  if (e < E) atomicAdd(&counts[eidx[E + e]], 1);
}

__global__ __launch_bounds__(1024)
void k_scan(const int* __restrict__ counts, int* __restrict__ row_ptr) {
  __shared__ int ssum[1024];
  const int t = threadIdx.x;
  const int CH = 49;
  int lo = t * CH, hi = min(lo + CH, N);
  int s = 0;
  for (int i = lo; i < hi; i++) s += counts[i];
  ssum[t] = s;
  __syncthreads();
  for (int off = 1; off < 1024; off <<= 1) {
    int v = (t >= off) ? ssum[t - off] : 0;
    __syncthreads();
    ssum[t] += v;
    __syncthreads();
  }
  int run = (t == 0) ? 0 : ssum[t - 1];
  for (int i = lo; i < hi; i++) { row_ptr[i] = run; run += counts[i]; }
  if (t == 1023) row_ptr[N] = ssum[1023];
}

__global__ void k_scatter(const int* __restrict__ eidx, const int* __restrict__ row_ptr,
                          int* __restrict__ woff, int* __restrict__ perm) {
  int e = blockIdx.x * 256 + threadIdx.x;
  if (e < E) {
    int d = eidx[E + e];
    int p = atomicAdd(&woff[d], 1);
    perm[row_ptr[d] + p] = e;
  }
}

// ---------------- Kernel INIT: fused prep + lin1 + zero(cnt/woff) + zero(aggs) ----------------
// All four are mutually independent; block-range partitioned. k_hist stays a
// separate dispatch (it atomically increments cnt -- fusing would race the zeroing).
__global__ __launch_bounds__(256)
void k_init(const float* __restrict__ Wsc0, const float* __restrict__ W3s,
            const float* __restrict__ Wsc1, const float* __restrict__ W3v,
            const float* __restrict__ W2s, const float* __restrict__ W2v,
            unsigned short* __restrict__ BT, unsigned short* __restrict__ B2T,
            unsigned short* __restrict__ w2sTg, unsigned short* __restrict__ w2vTg,
            const float* __restrict__ node_s, const float* __restrict__ node_v,
            const float* __restrict__ W1s, const float* __restrict__ W1v,
            float* __restrict__ s1, float* __restrict__ v1,
            int* __restrict__ cnt, float* __restrict__ aggs) {
  __shared__ float w1s[64 * 64];
  __shared__ float w1v[32 * 32];
  const int b = blockIdx.x, t = threadIdx.x;
  const float isq96 = 0.10206207261596575f;

  if (b < 528) {
    // ---- prep: bf16 transposed B matrices ----
    int i = b * 256 + t;
    if (i < 96 * 1088) {
      int j = i / 1088, k = i % 1088;
      float v;
      if (k < 1024) v = Wsc0[(size_t)k * 96 + j] * 0.03125f;          // 1/sqrt(1024)
      else          v = W3s[(size_t)(k - 1024) * 96 + j] * 0.125f;    // 1/sqrt(64)
      BT[i] = f2bf(v);
    } else if (i < 96 * 1088 + 32 * 576) {
      int i2 = i - 96 * 1088;
      int w = i2 / 576, k = i2 % 576;
      float v = 0.f;
      if (k < 512)      v = Wsc1[(size_t)k * 32 + w] * 0.04419417382415922f;  // 1/sqrt(512)
      else if (k < 544) v = W3v[(size_t)(k - 512) * 32 + w] * 0.17677669529663689f; // 1/sqrt(32)
      B2T[i2] = f2bf(v);
    } else if (i < 96 * 1088 + 32 * 576 + 96 * 96) {
      int i3 = i - (96 * 1088 + 32 * 576);
      int j = i3 / 96, k = i3 % 96;            // w2sTg[j][k] = W2s[k][j]
      w2sTg[i3] = f2bf(W2s[(size_t)k * 96 + j] * isq96);
    } else {
      int i4 = i - (96 * 1088 + 32 * 576 + 96 * 96);
      if (i4 < 32 * 96) {
        int v = i4 / 96, u = i4 % 96;          // w2vTg[v][u] = W2v[u][v]
        w2vTg[i4] = f2bf(W2v[(size_t)u * 32 + v] * isq96);
      }
    }
  } else if (b < 1552) {
    // ---- lin1: s1 = node_s@W1s/8 ; v1 = node_v x W1v /sqrt(32) ----
    for (int i = t; i < 64 * 64; i += 256) w1s[i] = W1s[i];
    for (int i = t; i < 32 * 32; i += 256) w1v[i] = W1v[i];
    __syncthreads();
    const float is_ns = 0.125f;
    const float is_nv = 0.17677669529663689f;
    int gtid = (b - 528) * 256 + t;
    const int stride = 1024 * 256;
    for (int i = gtid; i < N * 160; i += stride) {
      int n = i / 160, ch = i % 160;
      if (ch < 64) {
        const float* row = node_s + n * 64;
        float acc = 0.f;
#pragma unroll
        for (int u = 0; u < 64; u++) acc += row[u] * w1s[u * 64 + ch];
        s1[n * 64 + ch] = acc * is_ns;
      } else {
        int p = ch - 64, v = p / 3, c = p % 3;
        const float* row = node_v + n * 96;
        float acc = 0.f;
#pragma unroll
        for (int u = 0; u < 32; u++) acc += row[u * 3 + c] * w1v[u * 32 + v];
        v1[n * 96 + p] = acc * is_nv;
      }
    }
  } else if (b < 1943) {
    // ---- zero cnt + woff (2N ints) ----
    if (cnt) {
      int idx = (b - 1552) * 256 + t;
      if (idx < 2 * N) cnt[idx] = 0;
    }
  } else {
    // ---- zero aggs + aggv (N*160 floats, 16B-aligned base) ----
    float4v* a4 = (float4v*)aggs;
    const int tot = N * 160 / 4;
    const float4v z = {0.f, 0.f, 0.f, 0.f};
    for (int i = (b - 1943) * 256 + t; i < tot; i += 2000 * 256) a4[i] = z;
  }
}

// ---------------- Kernel B: streaming per-edge message via MFMA + in-kernel CSR reduce ----------------
// R10-proven equilibrium: f32 msL/mvL, launch_bounds(256,4), grid 1024.
// Occupancy pushes FAIL both ways: R6 (grid 1536: prologue churn, -15%) and
// R11 (bounds(256,5): reg budget drops to ~102, AGPR B-fragments evicted ->
// per-pass global reloads, FETCH +286MB, -15%). 4 blk/CU + ~128 unified regs
// is the proven operating point -- do not touch.
template<int STORE>
__global__ __launch_bounds__(256, 4)
void k_msg(const float* __restrict__ s1, const float* __restrict__ v1,
           const float* __restrict__ emb, const float* __restrict__ sh0g,
           const float* __restrict__ sh1g, const int* __restrict__ eidx,
           const int* __restrict__ perm,
           const float* __restrict__ Wm1, const float* __restrict__ Wm2,
           const unsigned short* __restrict__ w2sTg, const unsigned short* __restrict__ w2vTg,
           float* __restrict__ aggs, float* __restrict__ aggv) {
  __shared__ float wm2s[192 * 9];             // staging, stride 9 (bank-safe)
  __shared__ float wm1s[64];
  __shared__ unsigned short tps[EPB * LDK];
  __shared__ unsigned short tpv[EPB * 3 * LDK];
  __shared__ float gat[EPB][33];              // padded: bank-conflict-free
  __shared__ float msL[EPB][65];              // per-pass m_s (f32, silu applied)
  __shared__ float mvL[EPB][97];              // per-pass m_v (f32, RAW -- gate in reduce)
  __shared__ float hb[EPB][8];
  __shared__ float sh1b[EPB][4];
  __shared__ float sh0b[EPB];
  __shared__ int ssrc[EPB];
  __shared__ int sdst[EPB];

  const int t = threadIdx.x;
  const int wave = t >> 6, lane = t & 63;
  const int lm = lane & 15, quad = lane >> 4;
  const int subc = t & 15;

  // ---- one-time staging ----
  for (int i = t; i < 192 * 8; i += 256) {
    int h = i / 192, c = i % 192;
    wm2s[c * 9 + h] = Wm2[i];
  }
  if (t < 64) wm1s[t] = Wm1[t];

  // ---- hoist MFMA B-fragments into registers (pass-invariant, AGPR-resident) ----
  short8 b1fr[2][3], b2fr[3];
  {
    const int nt0 = wave;
    const int nt1 = (wave + 4 < 6) ? wave + 4 : wave;   // waves 2,3: dup (unused)
    const int nv2 = wave & 1;                           // GEMM2: same for both tiles
#pragma unroll
    for (int kk = 0; kk < 3; kk++) {
      b1fr[0][kk] = *(const short8*)&w2sTg[(nt0 * 16 + lm) * 96 + kk * 32 + quad * 8];
      b1fr[1][kk] = *(const short8*)&w2sTg[(nt1 * 16 + lm) * 96 + kk * 32 + quad * 8];
      b2fr[kk]    = *(const short8*)&w2vTg[(nv2 * 16 + lm) * 96 + kk * 32 + quad * 8];
    }
  }
  __syncthreads();

  for (int pass = blockIdx.x; pass < E / EPB; pass += gridDim.x) {
    const int ebase = pass * EPB;
    __syncthreads();   // prev pass's reduce/GEMM reads done before overwrite
    // ---- phase A: stage edge meta + radial MLP hidden (disjoint threads) ----
    if (t < EPB) {
      const int e = STORE ? perm[ebase + t] : (ebase + t);
      ssrc[t] = eidx[e];
      sdst[t] = eidx[E + e];
      sh0b[t] = sh0g[e];
    } else if (t >= 64 && t < 64 + EPB * 3) {
      int i = t - 64;
      const int el = i / 3, c = i % 3;
      const int e = STORE ? perm[ebase + el] : (ebase + el);
      sh1b[el][c] = sh1g[e * 3 + c];
    } else if (t >= 128) {
      int i = t - 128, el = i >> 3, sub = i & 7;
      const int e = STORE ? perm[ebase + el] : (ebase + el);
      float acc = 0.f;
#pragma unroll
      for (int r = 0; r < 8; r++) acc += emb[e * 8 + r] * wm1s[r * 8 + sub];
      hb[el][sub] = silu_f(acc);
    }
    __syncthreads();
    // ---- phase B: build TPS / TPV (bf16); Wm2 read explicitly from LDS ----
    {
      const int el = t >> 4, sub = subc;
      const int src = ssrc[el];
      const float s0v = sh0b[el];
      const float x0 = sh1b[el][0], x1 = sh1b[el][1], x2 = sh1b[el][2];
      float hr[8];
#pragma unroll
      for (int h = 0; h < 8; h++) hr[h] = hb[el][h];
      const float4v ss = *(const float4v*)&s1[(size_t)src * 64 + sub * 4];
      unsigned short tsv[4], tvv[3][4];
#pragma unroll
      for (int i = 0; i < 4; i++) {
        float w0a = 0.f, w1a = 0.f;
#pragma unroll
        for (int h = 0; h < 8; h++) {
          w0a += hr[h] * wm2s[(sub * 4 + i) * 9 + h];
          w1a += hr[h] * wm2s[(64 + sub * 4 + i) * 9 + h];
        }
        const float ssu = ss[i];
        tsv[i] = f2bf(w0a * ssu * s0v);
        const float base = w1a * ssu;
        tvv[0][i] = f2bf(base * x0);
        tvv[1][i] = f2bf(base * x1);
        tvv[2][i] = f2bf(base * x2);
      }
      *(uint2*)&tps[el * LDK + sub * 4] = *(uint2*)tsv;
#pragma unroll
      for (int c = 0; c < 3; c++)
        *(uint2*)&tpv[(el * 3 + c) * LDK + sub * 4] = *(uint2*)tvv[c];
      const float2* vp = (const float2*)&v1[(size_t)src * 96 + sub * 6];
      const float2 va = vp[0], vb = vp[1], vc = vp[2];
      const float v6[6] = {va.x, va.y, vb.x, vb.y, vc.x, vc.y};
      unsigned short ts2[2], tv2[3][2];
#pragma unroll
      for (int i2 = 0; i2 < 2; i2++) {
        float w1b = 0.f, w0b = 0.f;
#pragma unroll
        for (int h = 0; h < 8; h++) {
          w1b += hr[h] * wm2s[(128 + sub * 2 + i2) * 9 + h];
          w0b += hr[h] * wm2s[(160 + sub * 2 + i2) * 9 + h];
        }
        const float vx = v6[i2 * 3 + 0], vy = v6[i2 * 3 + 1], vz = v6[i2 * 3 + 2];
        ts2[i2] = f2bf(w0b * (vx * x0 + vy * x1 + vz * x2));
        tv2[0][i2] = f2bf(w1b * vx * s0v);
        tv2[1][i2] = f2bf(w1b * vy * s0v);
        tv2[2][i2] = f2bf(w1b * vz * s0v);
      }
      *(unsigned*)&tps[el * LDK + 64 + sub * 2] = *(unsigned*)ts2;
#pragma unroll
      for (int c = 0; c < 3; c++)
        *(unsigned*)&tpv[(el * 3 + c) * LDK + 64 + sub * 2] = *(unsigned*)tv2[c];
    }
    __syncthreads();
    if (STORE) {
      // ---- fused MFMA phase: 12 tiles (6 G1 + 6 G2), 3 per wave, no idle ----
      short8 afr[3];
#pragma unroll
      for (int kk = 0; kk < 3; kk++)
        afr[kk] = *(const short8*)&tps[lm * LDK + kk * 32 + quad * 8];
#pragma unroll
      for (int tt = 0; tt < 3; tt++) {
        const int id = wave + tt * 4;   // 0..11
        float4v acc = {0.f, 0.f, 0.f, 0.f};
        if (id < 6) {
          // GEMM1 tile nt=id; b1fr index: id==wave -> 0, id==wave+4 -> 1
          const int t2 = id >> 2;
#pragma unroll
          for (int kk = 0; kk < 3; kk++)
            acc = __builtin_amdgcn_mfma_f32_16x16x32_bf16(afr[kk], b1fr[t2][kk], acc, 0, 0, 0);
          const int j = id * 16 + lm;
#pragma unroll
          for (int reg = 0; reg < 4; reg++) {
            const int e = quad * 4 + reg;
            const float val = acc[reg];
            if (j < 64) msL[e][j] = silu_f(val);
            else        gat[e][j - 64] = sigm_f(val);
          }
        } else {
          // GEMM2 tile g2=id-6: mt=g2>>1, nt2=g2&1 (nt2 == wave&1 always)
          const int g2 = id - 6;
          const int mt = g2 >> 1, nt2 = g2 & 1;
#pragma unroll
          for (int kk = 0; kk < 3; kk++) {
            short8 a = *(const short8*)&tpv[(mt * 16 + lm) * LDK + kk * 32 + quad * 8];
            acc = __builtin_amdgcn_mfma_f32_16x16x32_bf16(a, b2fr[kk], acc, 0, 0, 0);
          }
          const int v = nt2 * 16 + lm;
#pragma unroll
          for (int reg = 0; reg < 4; reg++) {
            const int r = mt * 16 + quad * 4 + reg;
            const int e = (r * 171) >> 9, c = r - 3 * e;
            mvL[e][v * 3 + c] = acc[reg];   // RAW: gate applied in reduce
          }
        }
      }
      __syncthreads();
      // ---- segment-reduce over consecutive equal-dst slots; gate folded in ----
      if (t < 160) {
        const int col = t - 64;                 // valid for t >= 64
        const int gv = (col * 171) >> 9;        // col/3
        float acc = 0.f;
        int cur = sdst[0];
        for (int s2 = 0; s2 < EPB; s2++) {
          const int d = sdst[s2];               // wave-uniform
          const float val = (t < 64) ? msL[s2][t] : mvL[s2][col] * gat[s2][gv];
          if (d != cur) {
            if (t < 64) atomicAdd(&aggs[(size_t)cur * 64 + t], acc);
            else        atomicAdd(&aggv[(size_t)cur * 96 + col], acc);
            acc = 0.f; cur = d;
          }
          acc += val;
        }
        if (t < 64) atomicAdd(&aggs[(size_t)cur * 64 + t], acc);
        else        atomicAdd(&aggv[(size_t)cur * 96 + col], acc);
      }
    } else {
      // ---- fallback: GEMM1 -> barrier -> GEMM2, per-edge atomics ----
      {
        short8 afr[3];
#pragma unroll
        for (int kk = 0; kk < 3; kk++)
          afr[kk] = *(const short8*)&tps[lm * LDK + kk * 32 + quad * 8];
#pragma unroll
        for (int t2 = 0; t2 < 2; t2++) {
          const int nt = wave + t2 * 4;
          if (nt < 6) {
            float4v acc = {0.f, 0.f, 0.f, 0.f};
#pragma unroll
            for (int kk = 0; kk < 3; kk++)
              acc = __builtin_amdgcn_mfma_f32_16x16x32_bf16(afr[kk], b1fr[t2][kk], acc, 0, 0, 0);
            const int j = nt * 16 + lm;
#pragma unroll
            for (int reg = 0; reg < 4; reg++) {
              const int e = quad * 4 + reg;
              const float val = acc[reg];
              if (j < 64) atomicAdd(&aggs[(size_t)sdst[e] * 64 + j], silu_f(val));
              else        gat[e][j - 64] = sigm_f(val);
            }
          }
        }
      }
      __syncthreads();
#pragma unroll
      for (int t2 = 0; t2 < 2; t2++) {
        const int tile = wave + t2 * 4;
        if (tile < 6) {
          const int mt = tile >> 1, nt2 = tile & 1;
          float4v acc = {0.f, 0.f, 0.f, 0.f};
#pragma unroll
          for (int kk = 0; kk < 3; kk++) {
            short8 a = *(const short8*)&tpv[(mt * 16 + lm) * LDK + kk * 32 + quad * 8];
            acc = __builtin_amdgcn_mfma_f32_16x16x32_bf16(a, b2fr[kk], acc, 0, 0, 0);
          }
          const int v = nt2 * 16 + lm;
#pragma unroll
          for (int reg = 0; reg < 4; reg++) {
            const int r = mt * 16 + quad * 4 + reg;
            const int e = (r * 171) >> 9, c = r - 3 * e;
            atomicAdd(&aggv[(size_t)sdst[e] * 96 + v * 3 + c], acc[reg] * gat[e][v]);
          }
        }
      }
    }
  }
}

// ---------------- Kernel C1: MFMA GEMM  [32 nodes x 1088] @ BT^T -> 96 cols ----------------
// R9-proven: per-lane register A-fragments, 2 barriers total, padded LDS rows.
__global__ __launch_bounds__(256, 4)
void k_c1(const float* __restrict__ node_s, const float* __restrict__ attrs,
          const float* __restrict__ aggs, const float* __restrict__ Wt0,
          const unsigned short* __restrict__ BT,
          float* __restrict__ out, float* __restrict__ gates) {
  __shared__ float s_row[32][65];
  __shared__ float attr[32][16];
  __shared__ float t0[32][65];
  __shared__ float wt0[1024];
  const int t = threadIdx.x;
  const int wave = t >> 6, lane = t & 63, lm = lane & 15, quad = lane >> 4;
  const int nbase = blockIdx.x * 32;

  for (int i = t; i < 1024; i += 256) wt0[i] = Wt0[i];
  for (int i = t; i < 2048; i += 256) {
    int nl = i >> 6, u = i & 63, n = nbase + nl;
    s_row[nl][u] = (n < N) ? node_s[(size_t)n * 64 + u] : 0.f;
    t0[nl][u]    = (n < N) ? aggs[(size_t)n * 64 + u] : 0.f;
  }
  for (int i = t; i < 512; i += 256) {
    int nl = i >> 4, a = i & 15, n = nbase + nl;
    attr[nl][a] = (n < N) ? attrs[(size_t)n * 16 + a] : 0.f;
  }
  __syncthreads();
  for (int i = t; i < 2048; i += 256) {
    int nl = i >> 6, u = i & 63;
    float d0 = 0.f;
#pragma unroll
    for (int a = 0; a < 16; a++) d0 += attr[nl][a] * wt0[u * 16 + a];
    t0[nl][u] *= d0 * 0.07216878364870322f;   // 1/(sqrt(16)*sqrt(12))
  }
  __syncthreads();

  // register-cache this lane's attr slices (rows lm and 16+lm, cols (quad&1)*8..+7)
  const int a0 = (quad & 1) * 8;
  float aA0[8], aA1[8];
#pragma unroll
  for (int i = 0; i < 8; i++) {
    aA0[i] = attr[lm][a0 + i];
    aA1[i] = attr[16 + lm][a0 + i];
  }

  float4v acc[3] = {{0,0,0,0},{0,0,0,0},{0,0,0,0}};
  int mts[3], nts[3];
#pragma unroll
  for (int tt = 0; tt < 3; tt++) {
    const int tile = wave + tt * 4;    // 0..11 = mt*6+nt
    mts[tt] = tile / 6;
    nts[tt] = tile % 6;
  }

  for (int kc = 0; kc < 17; kc++) {
#pragma unroll
    for (int ks = 0; ks < 2; ks++) {
      unsigned short e0[8], e1[8];
      if (kc < 16) {
        const int u = kc * 4 + ks * 2 + (quad >> 1);
        const float s0v = s_row[lm][u];
        const float s1v = s_row[16 + lm][u];
#pragma unroll
        for (int i = 0; i < 8; i++) {
          e0[i] = f2bf(s0v * aA0[i]);
          e1[i] = f2bf(s1v * aA1[i]);
        }
      } else {
        const int c0 = ks * 32 + quad * 8;
#pragma unroll
        for (int i = 0; i < 8; i++) {
          e0[i] = f2bf(t0[lm][c0 + i]);
          e1[i] = f2bf(t0[16 + lm][c0 + i]);
        }
      }
      const short8 am0 = *(const short8*)e0;
      const short8 am1 = *(const short8*)e1;
#pragma unroll
      for (int tt = 0; tt < 3; tt++) {
        short8 b = *(const short8*)&BT[(size_t)(nts[tt] * 16 + lm) * 1088 + kc * 64 + ks * 32 + quad * 8];
        acc[tt] = __builtin_amdgcn_mfma_f32_16x16x32_bf16(mts[tt] ? am1 : am0, b, acc[tt], 0, 0, 0);
      }
    }
  }
#pragma unroll
  for (int tt = 0; tt < 3; tt++) {
    const int j = nts[tt] * 16 + lm;
#pragma unroll
    for (int reg = 0; reg < 4; reg++) {
      const int m = mts[tt] * 16 + quad * 4 + reg;
      const int n = nbase + m;
      if (n < N) {
        const float val = acc[tt][reg];
        if (j < 64) out[(size_t)n * 160 + j] = silu_f(val);
        else        gates[(size_t)n * 32 + (j - 64)] = sigm_f(val);
      }
    }
  }
}

// ---------------- Kernel C2: MFMA GEMM  [96 rows (32n x 3c) x 544] @ B2T^T -> 32 cols ----------------
// R9-proven: direct register A-fragments, 2 barriers, kc=8/ks=1 zero-A skipped.
__global__ __launch_bounds__(256, 4)
void k_c2(const float* __restrict__ node_v, const float* __restrict__ attrs,
          const float* __restrict__ aggv, const float* __restrict__ Wt1,
          const unsigned short* __restrict__ B2T, const float* __restrict__ gts,
          float* __restrict__ out) {
  __shared__ float nvs[32][97];
  __shared__ float t1s[32][97];
  __shared__ float attr[32][16];
  __shared__ float wt1[512];
  const int t = threadIdx.x;
  const int wave = t >> 6, lane = t & 63, lm = lane & 15, quad = lane >> 4;
  const int nbase = blockIdx.x * 32;

  for (int i = t; i < 512; i += 256) wt1[i] = Wt1[i];
  for (int i = t; i < 32 * 96; i += 256) {
    int nl = i / 96, rr = i % 96, n = nbase + nl;
    nvs[nl][rr] = (n < N) ? node_v[(size_t)n * 96 + rr] : 0.f;
    t1s[nl][rr] = (n < N) ? aggv[(size_t)n * 96 + rr] : 0.f;
  }
  for (int i = t; i < 512; i += 256) {
    int nl = i >> 4, a = i & 15, n = nbase + nl;
    attr[nl][a] = (n < N) ? attrs[(size_t)n * 16 + a] : 0.f;
  }
  __syncthreads();
  for (int i = t; i < 1024; i += 256) {
    int nl = i >> 5, u = i & 31;
    float d1 = 0.f;
#pragma unroll
    for (int a = 0; a < 16; a++) d1 += attr[nl][a] * wt1[u * 16 + a];
    d1 *= 0.07216878364870322f;
    t1s[nl][u * 3 + 0] *= d1; t1s[nl][u * 3 + 1] *= d1; t1s[nl][u * 3 + 2] *= d1;
  }
  __syncthreads();

  int nls[3], cs[3], nts[3], mts[3];
#pragma unroll
  for (int tt = 0; tt < 3; tt++) {
    const int tile = wave + tt * 4;   // 0..11 = mt*2+nt
    mts[tt] = tile >> 1;
    nts[tt] = tile & 1;
    const int row = mts[tt] * 16 + lm;
    nls[tt] = (row * 171) >> 9;
    cs[tt]  = row - 3 * nls[tt];
  }
  const int a0 = (quad & 1) * 8;
  float aA[3][8];
#pragma unroll
  for (int tt = 0; tt < 3; tt++)
#pragma unroll
    for (int i = 0; i < 8; i++) aA[tt][i] = attr[nls[tt]][a0 + i];

  float4v acc[3] = {{0,0,0,0},{0,0,0,0},{0,0,0,0}};

  for (int kc = 0; kc < 9; kc++) {
#pragma unroll
    for (int ks = 0; ks < 2; ks++) {
      if (kc == 8 && ks == 1) continue;   // k >= 544: A is all-zero
#pragma unroll
      for (int tt = 0; tt < 3; tt++) {
        unsigned short ev[8];
        if (kc < 8) {
          const int u = kc * 4 + ks * 2 + (quad >> 1);
          const float vv = nvs[nls[tt]][u * 3 + cs[tt]];
#pragma unroll
          for (int i = 0; i < 8; i++) ev[i] = f2bf(vv * aA[tt][i]);
        } else {
          // k = 512 + quad*8 + i  (ks == 0)
#pragma unroll
          for (int i = 0; i < 8; i++) ev[i] = f2bf(t1s[nls[tt]][(quad * 8 + i) * 3 + cs[tt]]);
        }
        const short8 a = *(const short8*)ev;
        short8 b = *(const short8*)&B2T[(size_t)(nts[tt] * 16 + lm) * 576 + kc * 64 + ks * 32 + quad * 8];
        acc[tt] = __builtin_amdgcn_mfma_f32_16x16x32_bf16(a, b, acc[tt], 0, 0, 0);
      }
    }
  }
#pragma unroll
  for (int tt = 0; tt < 3; tt++) {
    const int w = nts[tt] * 16 + lm;
#pragma unroll
    for (int reg = 0; reg < 4; reg++) {
      const int row = mts[tt] * 16 + quad * 4 + reg;
      const int nl = (row * 171) >> 9, c = row - 3 * nl;
      const int n = nbase + nl;
      if (n < N)
        out[(size_t)n * 160 + 64 + w * 3 + c] = acc[tt][reg] * gts[(size_t)n * 32 + w];
    }
  }
}

extern "C" void kernel_launch(void* const* d_in, const int* in_sizes, int n_in,
                              void* d_out, int out_size, void* d_ws, size_t ws_size,
                              hipStream_t stream) {
  const float* node_s = (const float*)d_in[0];
  const float* node_v = (const float*)d_in[1];
  const float* attrs  = (const float*)d_in[2];
  const float* emb    = (const float*)d_in[3];
  const float* sh0    = (const float*)d_in[4];
  const float* sh1    = (const float*)d_in[5];
  const int*   eidx   = (const int*)d_in[6];
  const float* W1s    = (const float*)d_in[7];
  const float* W1v    = (const float*)d_in[8];
  const float* Wm1    = (const float*)d_in[9];
  const float* Wm2    = (const float*)d_in[10];
  const float* W2s    = (const float*)d_in[11];
  const float* W2v    = (const float*)d_in[12];
  const float* Wt0    = (const float*)d_in[13];
  const float* Wt1    = (const float*)d_in[14];
  const float* W3s    = (const float*)d_in[15];
  const float* W3v    = (const float*)d_in[16];
  const float* Wsc0   = (const float*)d_in[17];
  const float* Wsc1   = (const float*)d_in[18];

  char* p = (char*)d_ws;
  float* s1  = (float*)p;  p += (size_t)N * 64 * 4;
  float* v1f = (float*)p;  p += (size_t)N * 96 * 4;
  float* gts = (float*)p;  p += (size_t)N * 32 * 4;
  unsigned short* BT    = (unsigned short*)p;  p += (size_t)96 * 1088 * 2;
  unsigned short* B2T   = (unsigned short*)p;  p += (size_t)32 * 576 * 2;
  unsigned short* w2sTg = (unsigned short*)p;  p += (size_t)96 * 96 * 2;
  unsigned short* w2vTg = (unsigned short*)p;  p += (size_t)32 * 96 * 2;
  char* pmode = p;
  size_t base = (size_t)(pmode - (char*)d_ws);
  // store path: rowp + cnt + woff + perm + align + aggs/aggv (f32, contiguous)
  size_t need_store = base + ((size_t)N + 1) * 4 + (size_t)N * 4 + (size_t)N * 4
                    + (size_t)E * 4 + 16 + (size_t)N * 160 * 4;
  const bool store = (ws_size >= need_store);

  if (store) {
    int* rowp = (int*)pmode;
    int* cnt  = rowp + (N + 1);
    int* woff = cnt + N;
    int* perm = woff + N;
    float* aggs = (float*)(((uintptr_t)(perm + E) + 15) & ~(uintptr_t)15);
    float* aggv = aggs + (size_t)N * 64;
    k_init<<<3943, 256, 0, stream>>>(Wsc0, W3s, Wsc1, W3v, W2s, W2v, BT, B2T, w2sTg, w2vTg,
                                     node_s, node_v, W1s, W1v, s1, v1f, cnt, aggs);
    k_hist<<<(E + 255) / 256, 256, 0, stream>>>(eidx, cnt);
    k_scan<<<1, 1024, 0, stream>>>(cnt, rowp);
    k_scatter<<<(E + 255) / 256, 256, 0, stream>>>(eidx, rowp, woff, perm);
    k_msg<1><<<1024, 256, 0, stream>>>(s1, v1f, emb, sh0, sh1, eidx, perm, Wm1, Wm2,
                                       w2sTg, w2vTg, aggs, aggv);
    k_c1<<<1563, 256, 0, stream>>>(node_s, attrs, aggs, Wt0, BT, (float*)d_out, gts);
    k_c2<<<1563, 256, 0, stream>>>(node_v, attrs, aggv, Wt1, B2T, gts, (float*)d_out);
  } else {
    float* aggs = (float*)pmode;
    float* aggv = aggs + (size_t)N * 64;
    k_init<<<3943, 256, 0, stream>>>(Wsc0, W3s, Wsc1, W3v, W2s, W2v, BT, B2T, w2sTg, w2vTg,
                                     node_s, node_v, W1s, W1v, s1, v1f, nullptr, aggs);
    k_msg<0><<<1024, 256, 0, stream>>>(s1, v1f, emb, sh0, sh1, eidx, nullptr, Wm1, Wm2,
                                       w2sTg, w2vTg, aggs, aggv);
    k_c1<<<1563, 256, 0, stream>>>(node_s, attrs, aggs, Wt0, BT, (float*)d_out, gts);
    k_c2<<<1563, 256, 0, stream>>>(node_v, attrs, aggv, Wt1, B2T, gts, (float*)d_out);
  }
}

// Round 13
// 678.308 us; speedup vs baseline: 1.0648x; 1.0021x over previous
//
#include <hip/hip_runtime.h>
#include <math.h>
#include <stdint.h>

#define N 50000
#define E 600000
#define EPB 16     // edges per pass
#define LDK 104    // padded K stride (bf16 elems) for tp tiles

typedef __attribute__((ext_vector_type(8))) short short8;
typedef __attribute__((ext_vector_type(4))) float float4v;

__device__ __forceinline__ float silu_f(float x) { return x / (1.f + __expf(-x)); }
__device__ __forceinline__ float sigm_f(float x) { return 1.f / (1.f + __expf(-x)); }
__device__ __forceinline__ unsigned short f2bf(float f) {
  unsigned u = __float_as_uint(f);
  u += 0x7fff + ((u >> 16) & 1);   // RNE
  return (unsigned short)(u >> 16);
}
__device__ __forceinline__ float bf2f(unsigned short u) {
  return __uint_as_float(((unsigned)u) << 16);
}
__device__ __forceinline__ float bf2f_lo(unsigned u) { return __uint_as_float(u << 16); }
__device__ __forceinline__ float bf2f_hi(unsigned u) { return __uint_as_float(u & 0xffff0000u); }

// ---------------- CSR build ----------------
__global__ void k_hist(const int* __restrict__ eidx, int* __restrict__ counts) {
  int e = blockIdx.x * 256 + threadIdx.x;
  if (e < E) atomicAdd(&counts[eidx[E + e]], 1);
}

__global__ __launch_bounds__(1024)
void k_scan(const int* __restrict__ counts, int* __restrict__ row_ptr) {
  __shared__ int ssum[1024];
  const int t = threadIdx.x;
  const int CH = 49;
  int lo = t * CH, hi = min(lo + CH, N);
  int s = 0;
  for (int i = lo; i < hi; i++) s += counts[i];
  ssum[t] = s;
  __syncthreads();
  for (int off = 1; off < 1024; off <<= 1) {
    int v = (t >= off) ? ssum[t - off] : 0;
    __syncthreads();
    ssum[t] += v;
    __syncthreads();
  }
  int run = (t == 0) ? 0 : ssum[t - 1];
  for (int i = lo; i < hi; i++) { row_ptr[i] = run; run += counts[i]; }
  if (t == 1023) row_ptr[N] = ssum[1023];
}

__global__ void k_scatter(const int* __restrict__ eidx, const int* __restrict__ row_ptr,
                          int* __restrict__ woff, int* __restrict__ perm) {
  int e = blockIdx.x * 256 + threadIdx.x;
  if (e < E) {
    int d = eidx[E + e];
    int p = atomicAdd(&woff[d], 1);
    perm[row_ptr[d] + p] = e;
  }
}

// ---------------- Kernel INIT: fused prep + lin1(bf16 out) + zero(cnt/woff) + zero(aggs) ----------------
// R13: lin1 writes s1/v1 as bf16 -- k_msg's dominant cost is the 600K x 640B
// per-edge s1/v1 row gather (~384MB, no L2 reuse); bf16 halves it. Phase B
// rounds these products to bf16 for the MFMA anyway.
__global__ __launch_bounds__(256)
void k_init(const float* __restrict__ Wsc0, const float* __restrict__ W3s,
            const float* __restrict__ Wsc1, const float* __restrict__ W3v,
            const float* __restrict__ W2s, const float* __restrict__ W2v,
            unsigned short* __restrict__ BT, unsigned short* __restrict__ B2T,
            unsigned short* __restrict__ w2sTg, unsigned short* __restrict__ w2vTg,
            const float* __restrict__ node_s, const float* __restrict__ node_v,
            const float* __restrict__ W1s, const float* __restrict__ W1v,
            unsigned short* __restrict__ s1b, unsigned short* __restrict__ v1b,
            int* __restrict__ cnt, float* __restrict__ aggs) {
  __shared__ float w1s[64 * 64];
  __shared__ float w1v[32 * 32];
  const int b = blockIdx.x, t = threadIdx.x;
  const float isq96 = 0.10206207261596575f;

  if (b < 528) {
    // ---- prep: bf16 transposed B matrices ----
    int i = b * 256 + t;
    if (i < 96 * 1088) {
      int j = i / 1088, k = i % 1088;
      float v;
      if (k < 1024) v = Wsc0[(size_t)k * 96 + j] * 0.03125f;          // 1/sqrt(1024)
      else          v = W3s[(size_t)(k - 1024) * 96 + j] * 0.125f;    // 1/sqrt(64)
      BT[i] = f2bf(v);
    } else if (i < 96 * 1088 + 32 * 576) {
      int i2 = i - 96 * 1088;
      int w = i2 / 576, k = i2 % 576;
      float v = 0.f;
      if (k < 512)      v = Wsc1[(size_t)k * 32 + w] * 0.04419417382415922f;  // 1/sqrt(512)
      else if (k < 544) v = W3v[(size_t)(k - 512) * 32 + w] * 0.17677669529663689f; // 1/sqrt(32)
      B2T[i2] = f2bf(v);
    } else if (i < 96 * 1088 + 32 * 576 + 96 * 96) {
      int i3 = i - (96 * 1088 + 32 * 576);
      int j = i3 / 96, k = i3 % 96;            // w2sTg[j][k] = W2s[k][j]
      w2sTg[i3] = f2bf(W2s[(size_t)k * 96 + j] * isq96);
    } else {
      int i4 = i - (96 * 1088 + 32 * 576 + 96 * 96);
      if (i4 < 32 * 96) {
        int v = i4 / 96, u = i4 % 96;          // w2vTg[v][u] = W2v[u][v]
        w2vTg[i4] = f2bf(W2v[(size_t)u * 32 + v] * isq96);
      }
    }
  } else if (b < 1552) {
    // ---- lin1 (bf16 outputs) ----
    for (int i = t; i < 64 * 64; i += 256) w1s[i] = W1s[i];
    for (int i = t; i < 32 * 32; i += 256) w1v[i] = W1v[i];
    __syncthreads();
    const float is_ns = 0.125f;
    const float is_nv = 0.17677669529663689f;
    int gtid = (b - 528) * 256 + t;
    const int stride = 1024 * 256;
    for (int i = gtid; i < N * 160; i += stride) {
      int n = i / 160, ch = i % 160;
      if (ch < 64) {
        const float* row = node_s + n * 64;
        float acc = 0.f;
#pragma unroll
        for (int u = 0; u < 64; u++) acc += row[u] * w1s[u * 64 + ch];
        s1b[n * 64 + ch] = f2bf(acc * is_ns);
      } else {
        int p = ch - 64, v = p / 3, c = p % 3;
        const float* row = node_v + n * 96;
        float acc = 0.f;
#pragma unroll
        for (int u = 0; u < 32; u++) acc += row[u * 3 + c] * w1v[u * 32 + v];
        v1b[n * 96 + p] = f2bf(acc * is_nv);
      }
    }
  } else if (b < 1943) {
    // ---- zero cnt + woff (2N ints) ----
    if (cnt) {
      int idx = (b - 1552) * 256 + t;
      if (idx < 2 * N) cnt[idx] = 0;
    }
  } else {
    // ---- zero aggs + aggv (N*160 floats, 16B-aligned base) ----
    float4v* a4 = (float4v*)aggs;
    const int tot = N * 160 / 4;
    const float4v z = {0.f, 0.f, 0.f, 0.f};
    for (int i = (b - 1943) * 256 + t; i < tot; i += 2000 * 256) a4[i] = z;
  }
}

// ---------------- Kernel B: streaming per-edge message via MFMA + in-kernel CSR reduce ----------------
// R10-proven equilibrium: f32 msL/mvL, launch_bounds(256,4), grid 1024.
// Occupancy pushes FAIL both ways (R6 grid-push, R11 bounds-push: AGPR B-frag
// eviction). 4 blk/CU + ~128 unified regs is the operating point -- do not touch.
// R13: s1/v1 gathered as bf16 (halves the dominant FETCH component).
template<int STORE>
__global__ __launch_bounds__(256, 4)
void k_msg(const unsigned short* __restrict__ s1b, const unsigned short* __restrict__ v1b,
           const float* __restrict__ emb, const float* __restrict__ sh0g,
           const float* __restrict__ sh1g, const int* __restrict__ eidx,
           const int* __restrict__ perm,
           const float* __restrict__ Wm1, const float* __restrict__ Wm2,
           const unsigned short* __restrict__ w2sTg, const unsigned short* __restrict__ w2vTg,
           float* __restrict__ aggs, float* __restrict__ aggv) {
  __shared__ float wm2s[192 * 9];             // staging, stride 9 (bank-safe)
  __shared__ float wm1s[64];
  __shared__ unsigned short tps[EPB * LDK];
  __shared__ unsigned short tpv[EPB * 3 * LDK];
  __shared__ float gat[EPB][33];              // padded: bank-conflict-free
  __shared__ float msL[EPB][65];              // per-pass m_s (f32, silu applied)
  __shared__ float mvL[EPB][97];              // per-pass m_v (f32, RAW -- gate in reduce)
  __shared__ float hb[EPB][8];
  __shared__ float sh1b[EPB][4];
  __shared__ float sh0b[EPB];
  __shared__ int ssrc[EPB];
  __shared__ int sdst[EPB];

  const int t = threadIdx.x;
  const int wave = t >> 6, lane = t & 63;
  const int lm = lane & 15, quad = lane >> 4;
  const int subc = t & 15;

  // ---- one-time staging ----
  for (int i = t; i < 192 * 8; i += 256) {
    int h = i / 192, c = i % 192;
    wm2s[c * 9 + h] = Wm2[i];
  }
  if (t < 64) wm1s[t] = Wm1[t];

  // ---- hoist MFMA B-fragments into registers (pass-invariant, AGPR-resident) ----
  short8 b1fr[2][3], b2fr[3];
  {
    const int nt0 = wave;
    const int nt1 = (wave + 4 < 6) ? wave + 4 : wave;   // waves 2,3: dup (unused)
    const int nv2 = wave & 1;                           // GEMM2: same for both tiles
#pragma unroll
    for (int kk = 0; kk < 3; kk++) {
      b1fr[0][kk] = *(const short8*)&w2sTg[(nt0 * 16 + lm) * 96 + kk * 32 + quad * 8];
      b1fr[1][kk] = *(const short8*)&w2sTg[(nt1 * 16 + lm) * 96 + kk * 32 + quad * 8];
      b2fr[kk]    = *(const short8*)&w2vTg[(nv2 * 16 + lm) * 96 + kk * 32 + quad * 8];
    }
  }
  __syncthreads();

  for (int pass = blockIdx.x; pass < E / EPB; pass += gridDim.x) {
    const int ebase = pass * EPB;
    __syncthreads();   // prev pass's reduce/GEMM reads done before overwrite
    // ---- phase A: stage edge meta + radial MLP hidden (disjoint threads) ----
    if (t < EPB) {
      const int e = STORE ? perm[ebase + t] : (ebase + t);
      ssrc[t] = eidx[e];
      sdst[t] = eidx[E + e];
      sh0b[t] = sh0g[e];
    } else if (t >= 64 && t < 64 + EPB * 3) {
      int i = t - 64;
      const int el = i / 3, c = i % 3;
      const int e = STORE ? perm[ebase + el] : (ebase + el);
      sh1b[el][c] = sh1g[e * 3 + c];
    } else if (t >= 128) {
      int i = t - 128, el = i >> 3, sub = i & 7;
      const int e = STORE ? perm[ebase + el] : (ebase + el);
      float acc = 0.f;
#pragma unroll
      for (int r = 0; r < 8; r++) acc += emb[e * 8 + r] * wm1s[r * 8 + sub];
      hb[el][sub] = silu_f(acc);
    }
    __syncthreads();
    // ---- phase B: build TPS / TPV (bf16); s1/v1 gathered as bf16 ----
    {
      const int el = t >> 4, sub = subc;
      const int src = ssrc[el];
      const float s0v = sh0b[el];
      const float x0 = sh1b[el][0], x1 = sh1b[el][1], x2 = sh1b[el][2];
      float hr[8];
#pragma unroll
      for (int h = 0; h < 8; h++) hr[h] = hb[el][h];
      const unsigned* sp = (const unsigned*)(s1b + (size_t)src * 64 + sub * 4);
      const unsigned sw0 = sp[0], sw1 = sp[1];
      const float ssv[4] = { bf2f_lo(sw0), bf2f_hi(sw0), bf2f_lo(sw1), bf2f_hi(sw1) };
      unsigned short tsv[4], tvv[3][4];
#pragma unroll
      for (int i = 0; i < 4; i++) {
        float w0a = 0.f, w1a = 0.f;
#pragma unroll
        for (int h = 0; h < 8; h++) {
          w0a += hr[h] * wm2s[(sub * 4 + i) * 9 + h];
          w1a += hr[h] * wm2s[(64 + sub * 4 + i) * 9 + h];
        }
        const float ssu = ssv[i];
        tsv[i] = f2bf(w0a * ssu * s0v);
        const float base = w1a * ssu;
        tvv[0][i] = f2bf(base * x0);
        tvv[1][i] = f2bf(base * x1);
        tvv[2][i] = f2bf(base * x2);
      }
      *(uint2*)&tps[el * LDK + sub * 4] = *(uint2*)tsv;
#pragma unroll
      for (int c = 0; c < 3; c++)
        *(uint2*)&tpv[(el * 3 + c) * LDK + sub * 4] = *(uint2*)tvv[c];
      const unsigned* vp = (const unsigned*)(v1b + (size_t)src * 96 + sub * 6);
      const unsigned vw0 = vp[0], vw1 = vp[1], vw2 = vp[2];
      const float v6[6] = { bf2f_lo(vw0), bf2f_hi(vw0), bf2f_lo(vw1),
                            bf2f_hi(vw1), bf2f_lo(vw2), bf2f_hi(vw2) };
      unsigned short ts2[2], tv2[3][2];
#pragma unroll
      for (int i2 = 0; i2 < 2; i2++) {
        float w1b = 0.f, w0b = 0.f;
#pragma unroll
        for (int h = 0; h < 8; h++) {
          w1b += hr[h] * wm2s[(128 + sub * 2 + i2) * 9 + h];
          w0b += hr[h] * wm2s[(160 + sub * 2 + i2) * 9 + h];
        }
        const float vx = v6[i2 * 3 + 0], vy = v6[i2 * 3 + 1], vz = v6[i2 * 3 + 2];
        ts2[i2] = f2bf(w0b * (vx * x0 + vy * x1 + vz * x2));
        tv2[0][i2] = f2bf(w1b * vx * s0v);
        tv2[1][i2] = f2bf(w1b * vy * s0v);
        tv2[2][i2] = f2bf(w1b * vz * s0v);
      }
      *(unsigned*)&tps[el * LDK + 64 + sub * 2] = *(unsigned*)ts2;
#pragma unroll
      for (int c = 0; c < 3; c++)
        *(unsigned*)&tpv[(el * 3 + c) * LDK + 64 + sub * 2] = *(unsigned*)tv2[c];
    }
    __syncthreads();
    if (STORE) {
      // ---- fused MFMA phase: 12 tiles (6 G1 + 6 G2), 3 per wave, no idle ----
      short8 afr[3];
#pragma unroll
      for (int kk = 0; kk < 3; kk++)
        afr[kk] = *(const short8*)&tps[lm * LDK + kk * 32 + quad * 8];
#pragma unroll
      for (int tt = 0; tt < 3; tt++) {
        const int id = wave + tt * 4;   // 0..11
        float4v acc = {0.f, 0.f, 0.f, 0.f};
        if (id < 6) {
          const int t2 = id >> 2;
#pragma unroll
          for (int kk = 0; kk < 3; kk++)
            acc = __builtin_amdgcn_mfma_f32_16x16x32_bf16(afr[kk], b1fr[t2][kk], acc, 0, 0, 0);
          const int j = id * 16 + lm;
#pragma unroll
          for (int reg = 0; reg < 4; reg++) {
            const int e = quad * 4 + reg;
            const float val = acc[reg];
            if (j < 64) msL[e][j] = silu_f(val);
            else        gat[e][j - 64] = sigm_f(val);
          }
        } else {
          const int g2 = id - 6;
          const int mt = g2 >> 1, nt2 = g2 & 1;
#pragma unroll
          for (int kk = 0; kk < 3; kk++) {
            short8 a = *(const short8*)&tpv[(mt * 16 + lm) * LDK + kk * 32 + quad * 8];
            acc = __builtin_amdgcn_mfma_f32_16x16x32_bf16(a, b2fr[kk], acc, 0, 0, 0);
          }
          const int v = nt2 * 16 + lm;
#pragma unroll
          for (int reg = 0; reg < 4; reg++) {
            const int r = mt * 16 + quad * 4 + reg;
            const int e = (r * 171) >> 9, c = r - 3 * e;
            mvL[e][v * 3 + c] = acc[reg];   // RAW: gate applied in reduce
          }
        }
      }
      __syncthreads();
      // ---- segment-reduce over consecutive equal-dst slots; gate folded in ----
      if (t < 160) {
        const int col = t - 64;                 // valid for t >= 64
        const int gv = (col * 171) >> 9;        // col/3
        float acc = 0.f;
        int cur = sdst[0];
        for (int s2 = 0; s2 < EPB; s2++) {
          const int d = sdst[s2];               // wave-uniform
          const float val = (t < 64) ? msL[s2][t] : mvL[s2][col] * gat[s2][gv];
          if (d != cur) {
            if (t < 64) atomicAdd(&aggs[(size_t)cur * 64 + t], acc);
            else        atomicAdd(&aggv[(size_t)cur * 96 + col], acc);
            acc = 0.f; cur = d;
          }
          acc += val;
        }
        if (t < 64) atomicAdd(&aggs[(size_t)cur * 64 + t], acc);
        else        atomicAdd(&aggv[(size_t)cur * 96 + col], acc);
      }
    } else {
      // ---- fallback: GEMM1 -> barrier -> GEMM2, per-edge atomics ----
      {
        short8 afr[3];
#pragma unroll
        for (int kk = 0; kk < 3; kk++)
          afr[kk] = *(const short8*)&tps[lm * LDK + kk * 32 + quad * 8];
#pragma unroll
        for (int t2 = 0; t2 < 2; t2++) {
          const int nt = wave + t2 * 4;
          if (nt < 6) {
            float4v acc = {0.f, 0.f, 0.f, 0.f};
#pragma unroll
            for (int kk = 0; kk < 3; kk++)
              acc = __builtin_amdgcn_mfma_f32_16x16x32_bf16(afr[kk], b1fr[t2][kk], acc, 0, 0, 0);
            const int j = nt * 16 + lm;
#pragma unroll
            for (int reg = 0; reg < 4; reg++) {
              const int e = quad * 4 + reg;
              const float val = acc[reg];
              if (j < 64) atomicAdd(&aggs[(size_t)sdst[e] * 64 + j], silu_f(val));
              else        gat[e][j - 64] = sigm_f(val);
            }
          }
        }
      }
      __syncthreads();
#pragma unroll
      for (int t2 = 0; t2 < 2; t2++) {
        const int tile = wave + t2 * 4;
        if (tile < 6) {
          const int mt = tile >> 1, nt2 = tile & 1;
          float4v acc = {0.f, 0.f, 0.f, 0.f};
#pragma unroll
          for (int kk = 0; kk < 3; kk++) {
            short8 a = *(const short8*)&tpv[(mt * 16 + lm) * LDK + kk * 32 + quad * 8];
            acc = __builtin_amdgcn_mfma_f32_16x16x32_bf16(a, b2fr[kk], acc, 0, 0, 0);
          }
          const int v = nt2 * 16 + lm;
#pragma unroll
          for (int reg = 0; reg < 4; reg++) {
            const int r = mt * 16 + quad * 4 + reg;
            const int e = (r * 171) >> 9, c = r - 3 * e;
            atomicAdd(&aggv[(size_t)sdst[e] * 96 + v * 3 + c], acc[reg] * gat[e][v]);
          }
        }
      }
    }
  }
}

// ---------------- Kernel CD: merged update GEMMs (R9 C1 + C2 bodies) ----------------
// Same resource profile for both phases (unlike the R5 gather/GEMM mismatch):
// one dispatch instead of two, no gts HBM round-trip, shared attrs staging.
// bufA (32x97 x2, stride-97 bank-safe) aliased between {s_row,t0} and {nvs,t1s};
// LDS total 35.2KB -> 4 blocks/CU.
__global__ __launch_bounds__(256, 4)
void k_cd(const float* __restrict__ node_s, const float* __restrict__ node_v,
          const float* __restrict__ attrs,
          const float* __restrict__ aggs, const float* __restrict__ aggv,
          const float* __restrict__ Wt0, const float* __restrict__ Wt1,
          const unsigned short* __restrict__ BT, const unsigned short* __restrict__ B2T,
          float* __restrict__ out) {
  __shared__ float bufA[2 * 32 * 97];
  __shared__ float attr[32][16];
  __shared__ float wtb[1024];
  __shared__ float gatesL[32][33];
  const int t = threadIdx.x;
  const int wave = t >> 6, lane = t & 63, lm = lane & 15, quad = lane >> 4;
  const int nbase = blockIdx.x * 32;

  // ======== phase C1: [32 x 1088] @ BT^T -> 96 cols ========
  {
    float* s_row = bufA;              // [32][97], cols 0..63 used
    float* t0    = bufA + 32 * 97;

    for (int i = t; i < 1024; i += 256) wtb[i] = Wt0[i];
    for (int i = t; i < 2048; i += 256) {
      int nl = i >> 6, u = i & 63, n = nbase + nl;
      s_row[nl * 97 + u] = (n < N) ? node_s[(size_t)n * 64 + u] : 0.f;
      t0[nl * 97 + u]    = (n < N) ? aggs[(size_t)n * 64 + u] : 0.f;
    }
    for (int i = t; i < 512; i += 256) {
      int nl = i >> 4, a = i & 15, n = nbase + nl;
      attr[nl][a] = (n < N) ? attrs[(size_t)n * 16 + a] : 0.f;
    }
    __syncthreads();
    for (int i = t; i < 2048; i += 256) {
      int nl = i >> 6, u = i & 63;
      float d0 = 0.f;
#pragma unroll
      for (int a = 0; a < 16; a++) d0 += attr[nl][a] * wtb[u * 16 + a];
      t0[nl * 97 + u] *= d0 * 0.07216878364870322f;   // 1/(sqrt(16)*sqrt(12))
    }
    __syncthreads();

    const int a0 = (quad & 1) * 8;
    float aA0[8], aA1[8];
#pragma unroll
    for (int i = 0; i < 8; i++) {
      aA0[i] = attr[lm][a0 + i];
      aA1[i] = attr[16 + lm][a0 + i];
    }

    float4v acc[3] = {{0,0,0,0},{0,0,0,0},{0,0,0,0}};
    int mts[3], nts[3];
#pragma unroll
    for (int tt = 0; tt < 3; tt++) {
      const int tile = wave + tt * 4;    // 0..11 = mt*6+nt
      mts[tt] = tile / 6;
      nts[tt] = tile % 6;
    }

    for (int kc = 0; kc < 17; kc++) {
#pragma unroll
      for (int ks = 0; ks < 2; ks++) {
        unsigned short e0[8], e1[8];
        if (kc < 16) {
          const int u = kc * 4 + ks * 2 + (quad >> 1);
          const float s0v = s_row[lm * 97 + u];
          const float s1v = s_row[(16 + lm) * 97 + u];
#pragma unroll
          for (int i = 0; i < 8; i++) {
            e0[i] = f2bf(s0v * aA0[i]);
            e1[i] = f2bf(s1v * aA1[i]);
          }
        } else {
          const int c0 = ks * 32 + quad * 8;
#pragma unroll
          for (int i = 0; i < 8; i++) {
            e0[i] = f2bf(t0[lm * 97 + c0 + i]);
            e1[i] = f2bf(t0[(16 + lm) * 97 + c0 + i]);
          }
        }
        const short8 am0 = *(const short8*)e0;
        const short8 am1 = *(const short8*)e1;
#pragma unroll
        for (int tt = 0; tt < 3; tt++) {
          short8 b = *(const short8*)&BT[(size_t)(nts[tt] * 16 + lm) * 1088 + kc * 64 + ks * 32 + quad * 8];
          acc[tt] = __builtin_amdgcn_mfma_f32_16x16x32_bf16(mts[tt] ? am1 : am0, b, acc[tt], 0, 0, 0);
        }
      }
    }
#pragma unroll
    for (int tt = 0; tt < 3; tt++) {
      const int j = nts[tt] * 16 + lm;
#pragma unroll
      for (int reg = 0; reg < 4; reg++) {
        const int m = mts[tt] * 16 + quad * 4 + reg;
        const int n = nbase + m;
        const float val = acc[tt][reg];
        if (j < 64) {
          if (n < N) out[(size_t)n * 160 + j] = silu_f(val);
        } else {
          gatesL[m][j - 64] = sigm_f(val);
        }
      }
    }
  }
  __syncthreads();   // bufA reads done; gatesL written

  // ======== phase C2: [96 rows (32n x 3c) x 544] @ B2T^T -> 32 cols ========
  {
    float* nvs = bufA;                // [32][97], cols 0..95 used
    float* t1s = bufA + 32 * 97;

    for (int i = t; i < 512; i += 256) wtb[i] = Wt1[i];
    for (int i = t; i < 32 * 96; i += 256) {
      int nl = i / 96, rr = i % 96, n = nbase + nl;
      nvs[nl * 97 + rr] = (n < N) ? node_v[(size_t)n * 96 + rr] : 0.f;
      t1s[nl * 97 + rr] = (n < N) ? aggv[(size_t)n * 96 + rr] : 0.f;
    }
    __syncthreads();
    for (int i = t; i < 1024; i += 256) {
      int nl = i >> 5, u = i & 31;
      float d1 = 0.f;
#pragma unroll
      for (int a = 0; a < 16; a++) d1 += attr[nl][a] * wtb[u * 16 + a];
      d1 *= 0.07216878364870322f;
      t1s[nl * 97 + u * 3 + 0] *= d1;
      t1s[nl * 97 + u * 3 + 1] *= d1;
      t1s[nl * 97 + u * 3 + 2] *= d1;
    }
    __syncthreads();

    int nls[3], cs[3], nts[3], mts[3];
#pragma unroll
    for (int tt = 0; tt < 3; tt++) {
      const int tile = wave + tt * 4;   // 0..11 = mt*2+nt
      mts[tt] = tile >> 1;
      nts[tt] = tile & 1;
      const int row = mts[tt] * 16 + lm;
      nls[tt] = (row * 171) >> 9;
      cs[tt]  = row - 3 * nls[tt];
    }
    const int a0 = (quad & 1) * 8;
    float aA[3][8];
#pragma unroll
    for (int tt = 0; tt < 3; tt++)
#pragma unroll
      for (int i = 0; i < 8; i++) aA[tt][i] = attr[nls[tt]][a0 + i];

    float4v acc[3] = {{0,0,0,0},{0,0,0,0},{0,0,0,0}};

    for (int kc = 0; kc < 9; kc++) {
#pragma unroll
      for (int ks = 0; ks < 2; ks++) {
        if (kc == 8 && ks == 1) continue;   // k >= 544: A is all-zero
#pragma unroll
        for (int tt = 0; tt < 3; tt++) {
          unsigned short ev[8];
          if (kc < 8) {
            const int u = kc * 4 + ks * 2 + (quad >> 1);
            const float vv = nvs[nls[tt] * 97 + u * 3 + cs[tt]];
#pragma unroll
            for (int i = 0; i < 8; i++) ev[i] = f2bf(vv * aA[tt][i]);
          } else {
            // k = 512 + quad*8 + i  (ks == 0)
#pragma unroll
            for (int i = 0; i < 8; i++) ev[i] = f2bf(t1s[nls[tt] * 97 + (quad * 8 + i) * 3 + cs[tt]]);
          }
          const short8 a = *(const short8*)ev;
          short8 b = *(const short8*)&B2T[(size_t)(nts[tt] * 16 + lm) * 576 + kc * 64 + ks * 32 + quad * 8];
          acc[tt] = __builtin_amdgcn_mfma_f32_16x16x32_bf16(a, b, acc[tt], 0, 0, 0);
        }
      }
    }
#pragma unroll
    for (int tt = 0; tt < 3; tt++) {
      const int w = nts[tt] * 16 + lm;
#pragma unroll
      for (int reg = 0; reg < 4; reg++) {
        const int row = mts[tt] * 16 + quad * 4 + reg;
        const int nl = (row * 171) >> 9, c = row - 3 * nl;
        const int n = nbase + nl;
        if (n < N)
          out[(size_t)n * 160 + 64 + w * 3 + c] = acc[tt][reg] * gatesL[nl][w];
      }
    }
  }
}

extern "C" void kernel_launch(void* const* d_in, const int* in_sizes, int n_in,
                              void* d_out, int out_size, void* d_ws, size_t ws_size,
                              hipStream_t stream) {
  const float* node_s = (const float*)d_in[0];
  const float* node_v = (const float*)d_in[1];
  const float* attrs  = (const float*)d_in[2];
  const float* emb    = (const float*)d_in[3];
  const float* sh0    = (const float*)d_in[4];
  const float* sh1    = (const float*)d_in[5];
  const int*   eidx   = (const int*)d_in[6];
  const float* W1s    = (const float*)d_in[7];
  const float* W1v    = (const float*)d_in[8];
  const float* Wm1    = (const float*)d_in[9];
  const float* Wm2    = (const float*)d_in[10];
  const float* W2s    = (const float*)d_in[11];
  const float* W2v    = (const float*)d_in[12];
  const float* Wt0    = (const float*)d_in[13];
  const float* Wt1    = (const float*)d_in[14];
  const float* W3s    = (const float*)d_in[15];
  const float* W3v    = (const float*)d_in[16];
  const float* Wsc0   = (const float*)d_in[17];
  const float* Wsc1   = (const float*)d_in[18];

  char* p = (char*)d_ws;
  unsigned short* s1b = (unsigned short*)p;  p += (size_t)N * 64 * 2;
  unsigned short* v1b = (unsigned short*)p;  p += (size_t)N * 96 * 2;
  unsigned short* BT    = (unsigned short*)p;  p += (size_t)96 * 1088 * 2;
  unsigned short* B2T   = (unsigned short*)p;  p += (size_t)32 * 576 * 2;
  unsigned short* w2sTg = (unsigned short*)p;  p += (size_t)96 * 96 * 2;
  unsigned short* w2vTg = (unsigned short*)p;  p += (size_t)32 * 96 * 2;
  char* pmode = p;
  size_t base = (size_t)(pmode - (char*)d_ws);
  // store path: rowp + cnt + woff + perm + align + aggs/aggv (f32, contiguous)
  size_t need_store = base + ((size_t)N + 1) * 4 + (size_t)N * 4 + (size_t)N * 4
                    + (size_t)E * 4 + 16 + (size_t)N * 160 * 4;
  const bool store = (ws_size >= need_store);

  if (store) {
    int* rowp = (int*)pmode;
    int* cnt  = rowp + (N + 1);
    int* woff = cnt + N;
    int* perm = woff + N;
    float* aggs = (float*)(((uintptr_t)(perm + E) + 15) & ~(uintptr_t)15);
    float* aggv = aggs + (size_t)N * 64;
    k_init<<<3943, 256, 0, stream>>>(Wsc0, W3s, Wsc1, W3v, W2s, W2v, BT, B2T, w2sTg, w2vTg,
                                     node_s, node_v, W1s, W1v, s1b, v1b, cnt, aggs);
    k_hist<<<(E + 255) / 256, 256, 0, stream>>>(eidx, cnt);
    k_scan<<<1, 1024, 0, stream>>>(cnt, rowp);
    k_scatter<<<(E + 255) / 256, 256, 0, stream>>>(eidx, rowp, woff, perm);
    k_msg<1><<<1024, 256, 0, stream>>>(s1b, v1b, emb, sh0, sh1, eidx, perm, Wm1, Wm2,
                                       w2sTg, w2vTg, aggs, aggv);
    k_cd<<<1563, 256, 0, stream>>>(node_s, node_v, attrs, aggs, aggv, Wt0, Wt1,
                                   BT, B2T, (float*)d_out);
  } else {
    float* aggs = (float*)(((uintptr_t)pmode + 15) & ~(uintptr_t)15);
    float* aggv = aggs + (size_t)N * 64;
    k_init<<<3943, 256, 0, stream>>>(Wsc0, W3s, Wsc1, W3v, W2s, W2v, BT, B2T, w2sTg, w2vTg,
                                     node_s, node_v, W1s, W1v, s1b, v1b, nullptr, aggs);
    k_msg<0><<<1024, 256, 0, stream>>>(s1b, v1b, emb, sh0, sh1, eidx, nullptr, Wm1, Wm2,
                                       w2sTg, w2vTg, aggs, aggv);
    k_cd<<<1563, 256, 0, stream>>>(node_s, node_v, attrs, aggs, aggv, Wt0, Wt1,
                                   BT, B2T, (float*)d_out);
  }
}